// Round 1
// baseline (1523.845 us; speedup 1.0000x reference)
//
#include <hip/hip_runtime.h>

#define D 128

// ---------------------------------------------------------------------------
// zero the aggregation workspace (harness poisons ws with 0xAA, never resets)
// ---------------------------------------------------------------------------
__global__ void zero_kernel(float4* __restrict__ p, size_t n4) {
    size_t i = (size_t)blockIdx.x * blockDim.x + threadIdx.x;
    size_t stride = (size_t)gridDim.x * blockDim.x;
    float4 z = make_float4(0.f, 0.f, 0.f, 0.f);
    for (; i < n4; i += stride) p[i] = z;
}

// ---------------------------------------------------------------------------
// scatter: agg[dst[e]] += x[src[e]] * w[e]
// one wave (64 lanes) per edge; lane handles 2 consecutive floats (float2).
// Gather read per edge = 512B contiguous (coalesced). 2 atomicAdds per lane.
// ---------------------------------------------------------------------------
__global__ __launch_bounds__(256) void scatter_kernel(
        const float* __restrict__ x,
        const int* __restrict__ ei,     // [2,E]: ei[0..E)=src, ei[E..2E)=dst
        const float* __restrict__ ew,   // [E]
        float* __restrict__ agg,
        int E) {
    int e = (int)(((size_t)blockIdx.x * blockDim.x + threadIdx.x) >> 6);
    if (e >= E) return;
    int lane = threadIdx.x & 63;

    int s = ei[e];
    int d = ei[e + E];
    float w = ew[e];

    float2 v = ((const float2*)(x + (size_t)s * D))[lane];
    float* ar = agg + (size_t)d * D + lane * 2;
    atomicAdd(ar,     v.x * w);
    atomicAdd(ar + 1, v.y * w);
}

// ---------------------------------------------------------------------------
// out = agg @ W2 + b2.   f32, no MFMA on CDNA4 -> vector ALU.
// W2 (128x128 f32 = 64KB) staged in LDS once per block.
// One wave per row; lane j computes output cols j and j+64.
// Ws[k][lane] access: 64 lanes stride-1 over 32 banks = 2-way alias (free).
// ---------------------------------------------------------------------------
__global__ __launch_bounds__(256) void gemm_kernel(
        const float* __restrict__ agg,
        const float* __restrict__ W2,
        const float* __restrict__ b2,
        float* __restrict__ out,
        int N) {
    __shared__ float Ws[D][D];
    for (int i = threadIdx.x; i < D * D / 4; i += blockDim.x)
        ((float4*)Ws)[i] = ((const float4*)W2)[i];
    __syncthreads();

    int lane = threadIdx.x & 63;
    int wave = threadIdx.x >> 6;
    int wavesPerBlock = blockDim.x >> 6;
    int totalWaves = gridDim.x * wavesPerBlock;

    float bj0 = b2[lane], bj1 = b2[lane + 64];

    for (int row = blockIdx.x * wavesPerBlock + wave; row < N; row += totalWaves) {
        const float* a = agg + (size_t)row * D;
        float acc0 = bj0, acc1 = bj1;
        #pragma unroll 8
        for (int k = 0; k < D; ++k) {
            float av = a[k];             // wave-uniform broadcast load
            acc0 = fmaf(av, Ws[k][lane],      acc0);
            acc1 = fmaf(av, Ws[k][lane + 64], acc1);
        }
        float* o = out + (size_t)row * D;
        o[lane]      = acc0;
        o[lane + 64] = acc1;
    }
}

extern "C" void kernel_launch(void* const* d_in, const int* in_sizes, int n_in,
                              void* d_out, int out_size, void* d_ws, size_t ws_size,
                              hipStream_t stream) {
    // inputs: 0=x[N,128] f32, 1=edge_index[2,E] int32, 2=edge_weight[E] f32,
    //         3=W1 (dead), 4=b1 (dead), 5=W2[128,128] f32, 6=b2[128] f32
    const float* x  = (const float*)d_in[0];
    const int*   ei = (const int*)d_in[1];
    const float* ew = (const float*)d_in[2];
    const float* W2 = (const float*)d_in[5];
    const float* b2 = (const float*)d_in[6];
    float* out = (float*)d_out;

    int N = in_sizes[0] / D;   // 100000
    int E = in_sizes[2];       // 1600000 (edge_weight element count)

    float* agg = (float*)d_ws; // N*D*4 = 51.2 MB scratch

    size_t n4 = (size_t)N * D / 4;
    zero_kernel<<<2048, 256, 0, stream>>>((float4*)agg, n4);

    int edgesPerBlock = 256 / 64;   // 4 waves -> 4 edges per block
    scatter_kernel<<<(E + edgesPerBlock - 1) / edgesPerBlock, 256, 0, stream>>>(
        x, ei, ew, agg, E);

    gemm_kernel<<<2048, 256, 0, stream>>>(agg, W2, b2, out, N);
}

// Round 2
// 550.848 us; speedup vs baseline: 2.7664x; 2.7664x over previous
//
#include <hip/hip_runtime.h>

#define D 128

// ---------------------------------------------------------------------------
// zero an int array (counts)
// ---------------------------------------------------------------------------
__global__ void zero_ints(int* __restrict__ p, int n) {
    int i = blockIdx.x * blockDim.x + threadIdx.x;
    if (i < n) p[i] = 0;
}

// ---------------------------------------------------------------------------
// histogram of destination nodes
// ---------------------------------------------------------------------------
__global__ __launch_bounds__(256) void hist_kernel(
        const int* __restrict__ ei, int* __restrict__ counts, int E) {
    int e = blockIdx.x * blockDim.x + threadIdx.x;
    if (e < E) atomicAdd(&counts[ei[E + e]], 1);
}

// ---------------------------------------------------------------------------
// single-block exclusive scan: offsets[0..n] (and cursor copy)
// 1024 threads x 8 items per chunk; LDS Hillis-Steele on thread totals.
// ---------------------------------------------------------------------------
#define SCAN_T 1024
#define SCAN_PER 8
__global__ __launch_bounds__(SCAN_T) void scan_kernel(
        const int* __restrict__ counts,
        int* __restrict__ offsets,
        int* __restrict__ cursor, int n) {
    __shared__ int sh[SCAN_T];
    __shared__ int carry_sh;
    int t = threadIdx.x;
    if (t == 0) carry_sh = 0;
    __syncthreads();
    const int CHUNK = SCAN_T * SCAN_PER;
    for (int base = 0; base < n; base += CHUNK) {
        int c[SCAN_PER], epre[SCAN_PER];
        int i0 = base + t * SCAN_PER;
        int run = 0;
        #pragma unroll
        for (int j = 0; j < SCAN_PER; ++j) {
            int i = i0 + j;
            c[j] = (i < n) ? counts[i] : 0;
            epre[j] = run;
            run += c[j];
        }
        sh[t] = run;
        __syncthreads();
        int val = run;
        for (int off = 1; off < SCAN_T; off <<= 1) {
            int other = (t >= off) ? sh[t - off] : 0;
            __syncthreads();
            val += other;
            sh[t] = val;
            __syncthreads();
        }
        int carry = carry_sh;              // last write was before the syncs above
        int excl = carry + val - run;      // exclusive prefix for this thread
        #pragma unroll
        for (int j = 0; j < SCAN_PER; ++j) {
            int i = i0 + j;
            if (i < n) {
                int o = excl + epre[j];
                offsets[i] = o;
                cursor[i]  = o;
            }
        }
        __syncthreads();
        if (t == SCAN_T - 1) carry_sh = carry + val;
        __syncthreads();
    }
    if (t == 0) offsets[n] = carry_sh;
}

// ---------------------------------------------------------------------------
// bucket edges by destination: sorted[pos] = (src, bits(weight))
// ---------------------------------------------------------------------------
__global__ __launch_bounds__(256) void bucket_kernel(
        const int* __restrict__ ei, const float* __restrict__ ew,
        int* __restrict__ cursor, int2* __restrict__ sorted, int E) {
    int e = blockIdx.x * blockDim.x + threadIdx.x;
    if (e >= E) return;
    int src = ei[e];
    int dst = ei[E + e];
    float w = ew[e];
    int pos = atomicAdd(&cursor[dst], 1);
    sorted[pos] = make_int2(src, __float_as_int(w));
}

// ---------------------------------------------------------------------------
// gather: one wave per destination node; lane handles a float2 (128 floats).
// x rows read as 512B coalesced wave loads (L3-resident). Zero atomics;
// agg written exactly once -> no zero-init of agg needed.
// ---------------------------------------------------------------------------
__global__ __launch_bounds__(256) void gather_kernel(
        const float* __restrict__ x,
        const int2* __restrict__ sorted,
        const int* __restrict__ offsets,
        float* __restrict__ agg, int N) {
    int node = (int)((((size_t)blockIdx.x * blockDim.x) + threadIdx.x) >> 6);
    if (node >= N) return;
    int lane = threadIdx.x & 63;

    int j   = offsets[node];
    int end = offsets[node + 1];
    float2 acc = make_float2(0.f, 0.f);
    for (; j + 1 < end; j += 2) {
        int2 s0 = sorted[j];
        int2 s1 = sorted[j + 1];
        float2 v0 = ((const float2*)(x + (size_t)s0.x * D))[lane];
        float2 v1 = ((const float2*)(x + (size_t)s1.x * D))[lane];
        float w0 = __int_as_float(s0.y);
        float w1 = __int_as_float(s1.y);
        acc.x = fmaf(v0.x, w0, acc.x);  acc.y = fmaf(v0.y, w0, acc.y);
        acc.x = fmaf(v1.x, w1, acc.x);  acc.y = fmaf(v1.y, w1, acc.y);
    }
    if (j < end) {
        int2 s0 = sorted[j];
        float2 v0 = ((const float2*)(x + (size_t)s0.x * D))[lane];
        float w0 = __int_as_float(s0.y);
        acc.x = fmaf(v0.x, w0, acc.x);  acc.y = fmaf(v0.y, w0, acc.y);
    }
    ((float2*)(agg + (size_t)node * D))[lane] = acc;
}

// ---------------------------------------------------------------------------
// out = agg @ W2 + b2 (f32 vector ALU; no fp32 MFMA on CDNA4).
// W2 in LDS; 8 rows per wave; A broadcast via v_readlane (VALU pipe, keeps
// the LDS pipe for the 4 W-reads per k-pair). Lane j owns cols j and j+64.
// ---------------------------------------------------------------------------
#define RPW 8   // rows per wave
__global__ __launch_bounds__(256) void gemm_kernel(
        const float* __restrict__ agg,
        const float* __restrict__ W2,
        const float* __restrict__ b2,
        float* __restrict__ out, int N) {
    __shared__ float Ws[D][D];
    for (int i = threadIdx.x; i < D * D / 4; i += blockDim.x)
        ((float4*)Ws)[i] = ((const float4*)W2)[i];
    __syncthreads();

    int lane = threadIdx.x & 63;
    int wave = threadIdx.x >> 6;
    int wavesPerBlock = blockDim.x >> 6;
    int globalWave = blockIdx.x * wavesPerBlock + wave;
    int totalWaves = gridDim.x * wavesPerBlock;

    float bj0 = b2[lane], bj1 = b2[lane + 64];

    for (int r0 = globalWave * RPW; r0 < N; r0 += totalWaves * RPW) {
        int nr = N - r0;  if (nr > RPW) nr = RPW;
        float2 a2[RPW];
        float acc0[RPW], acc1[RPW];
        #pragma unroll
        for (int i = 0; i < RPW; ++i) {
            a2[i] = (i < nr) ? ((const float2*)(agg + (size_t)(r0 + i) * D))[lane]
                             : make_float2(0.f, 0.f);
            acc0[i] = bj0;  acc1[i] = bj1;
        }
        #pragma unroll 8
        for (int kk = 0; kk < 64; ++kk) {          // covers k = 2kk, 2kk+1
            float w00 = Ws[2 * kk][lane];
            float w01 = Ws[2 * kk][lane + 64];
            float w10 = Ws[2 * kk + 1][lane];
            float w11 = Ws[2 * kk + 1][lane + 64];
            #pragma unroll
            for (int i = 0; i < RPW; ++i) {
                float a0 = __int_as_float(__builtin_amdgcn_readlane(__float_as_int(a2[i].x), kk));
                float a1 = __int_as_float(__builtin_amdgcn_readlane(__float_as_int(a2[i].y), kk));
                acc0[i] = fmaf(a0, w00, acc0[i]);
                acc1[i] = fmaf(a0, w01, acc1[i]);
                acc0[i] = fmaf(a1, w10, acc0[i]);
                acc1[i] = fmaf(a1, w11, acc1[i]);
            }
        }
        #pragma unroll
        for (int i = 0; i < RPW; ++i) {
            if (i < nr) {
                float* o = out + (size_t)(r0 + i) * D;
                o[lane]      = acc0[i];
                o[lane + 64] = acc1[i];
            }
        }
    }
}

extern "C" void kernel_launch(void* const* d_in, const int* in_sizes, int n_in,
                              void* d_out, int out_size, void* d_ws, size_t ws_size,
                              hipStream_t stream) {
    // inputs: 0=x[N,128] f32, 1=edge_index[2,E] int32, 2=edge_weight[E] f32,
    //         3=W1 (dead), 4=b1 (dead), 5=W2[128,128] f32, 6=b2[128] f32
    const float* x  = (const float*)d_in[0];
    const int*   ei = (const int*)d_in[1];
    const float* ew = (const float*)d_in[2];
    const float* W2 = (const float*)d_in[5];
    const float* b2 = (const float*)d_in[6];
    float* out = (float*)d_out;

    int N = in_sizes[0] / D;   // 100000
    int E = in_sizes[2];       // 1600000

    // scratch layout:
    //   d_ws : agg [N*D] f32                         (51.2 MB, proven size)
    //   d_out: CSR build area, consumed before GEMM overwrites d_out:
    //     [0, 8E)                    int2 sorted[E]      12.8 MB
    //     [8E, 8E+4(N+1))            int offsets[N+1]
    //     then                       int cursor[N]
    //     then                       int counts[N]
    float* agg = (float*)d_ws;
    char* scratch = (char*)d_out;
    int2* sorted  = (int2*)scratch;
    int* offsets  = (int*)(scratch + (size_t)E * 8);
    int* cursor   = offsets + (N + 1);
    int* counts   = cursor + N;

    zero_ints<<<(N + 255) / 256, 256, 0, stream>>>(counts, N);

    hist_kernel<<<(E + 255) / 256, 256, 0, stream>>>(ei, counts, E);

    scan_kernel<<<1, SCAN_T, 0, stream>>>(counts, offsets, cursor, N);

    bucket_kernel<<<(E + 255) / 256, 256, 0, stream>>>(ei, ew, cursor, sorted, E);

    // one wave per node: N*64 threads
    gather_kernel<<<(N * 64 + 255) / 256, 256, 0, stream>>>(x, sorted, offsets, agg, N);

    gemm_kernel<<<1024, 256, 0, stream>>>(agg, W2, b2, out, N);
}

// Round 3
// 411.526 us; speedup vs baseline: 3.7029x; 1.3385x over previous
//
#include <hip/hip_runtime.h>

#define D 128

// ---------------------------------------------------------------------------
// zero an int array (counts)
// ---------------------------------------------------------------------------
__global__ void zero_ints(int* __restrict__ p, int n) {
    int i = blockIdx.x * blockDim.x + threadIdx.x;
    if (i < n) p[i] = 0;
}

// ---------------------------------------------------------------------------
// histogram of destination nodes
// ---------------------------------------------------------------------------
__global__ __launch_bounds__(256) void hist_kernel(
        const int* __restrict__ ei, int* __restrict__ counts, int E) {
    int e = blockIdx.x * blockDim.x + threadIdx.x;
    if (e < E) atomicAdd(&counts[ei[E + e]], 1);
}

// ---------------------------------------------------------------------------
// multi-block exclusive scan of counts[n] -> offsets[n+1] (+ cursor copy)
// phase 1: per-block chunk sums;  phase 2: scan the ~98 partials (1 block);
// phase 3: block-local scan + add block offset.
// ---------------------------------------------------------------------------
#define SCAN_BT 256      // threads per scan block
#define SCAN_IT 4        // items per thread
#define SCAN_CHUNK (SCAN_BT * SCAN_IT)   // 1024 elements per block

__global__ __launch_bounds__(SCAN_BT) void scan_partials_reduce(
        const int* __restrict__ counts, int* __restrict__ partials, int n) {
    __shared__ int sh[SCAN_BT];
    int t = threadIdx.x;
    int base = blockIdx.x * SCAN_CHUNK;
    int s = 0;
    #pragma unroll
    for (int j = 0; j < SCAN_IT; ++j) {
        int i = base + t * SCAN_IT + j;
        if (i < n) s += counts[i];
    }
    sh[t] = s;
    __syncthreads();
    for (int off = SCAN_BT / 2; off > 0; off >>= 1) {
        if (t < off) sh[t] += sh[t + off];
        __syncthreads();
    }
    if (t == 0) partials[blockIdx.x] = sh[0];
}

// single block, nP <= blockDim.x partials
__global__ __launch_bounds__(1024) void scan_partials_scan(
        int* __restrict__ partials, int* __restrict__ offsets, int nP, int n) {
    __shared__ int sh[1024];
    int t = threadIdx.x;
    int v = (t < nP) ? partials[t] : 0;
    sh[t] = v;
    __syncthreads();
    int val = v;
    for (int off = 1; off < 1024; off <<= 1) {
        int other = (t >= off) ? sh[t - off] : 0;
        __syncthreads();
        val += other;
        sh[t] = val;
        __syncthreads();
    }
    if (t < nP) partials[t] = val - v;         // exclusive block offset
    if (t == 1023) offsets[n] = val;           // grand total
}

__global__ __launch_bounds__(SCAN_BT) void scan_final(
        const int* __restrict__ counts, const int* __restrict__ partials,
        int* __restrict__ offsets, int* __restrict__ cursor, int n) {
    __shared__ int sh[SCAN_BT];
    int t = threadIdx.x;
    int base = blockIdx.x * SCAN_CHUNK;
    int i0 = base + t * SCAN_IT;
    int c[SCAN_IT], pre[SCAN_IT];
    int run = 0;
    #pragma unroll
    for (int j = 0; j < SCAN_IT; ++j) {
        int i = i0 + j;
        c[j] = (i < n) ? counts[i] : 0;
        pre[j] = run;
        run += c[j];
    }
    sh[t] = run;
    __syncthreads();
    int val = run;
    for (int off = 1; off < SCAN_BT; off <<= 1) {
        int other = (t >= off) ? sh[t - off] : 0;
        __syncthreads();
        val += other;
        sh[t] = val;
        __syncthreads();
    }
    int excl = partials[blockIdx.x] + val - run;
    #pragma unroll
    for (int j = 0; j < SCAN_IT; ++j) {
        int i = i0 + j;
        if (i < n) {
            int o = excl + pre[j];
            offsets[i] = o;
            cursor[i]  = o;
        }
    }
}

// ---------------------------------------------------------------------------
// bucket edges by destination: sorted[pos] = (src, bits(weight))
// ---------------------------------------------------------------------------
__global__ __launch_bounds__(256) void bucket_kernel(
        const int* __restrict__ ei, const float* __restrict__ ew,
        int* __restrict__ cursor, int2* __restrict__ sorted, int E) {
    int e = blockIdx.x * blockDim.x + threadIdx.x;
    if (e >= E) return;
    int src = ei[e];
    int dst = ei[E + e];
    float w = ew[e];
    int pos = atomicAdd(&cursor[dst], 1);
    sorted[pos] = make_int2(src, __float_as_int(w));
}

// ---------------------------------------------------------------------------
// gather: one wave per destination node; lane handles a float2 (128 floats).
// x rows read as 512B coalesced wave loads (L3-resident). Zero atomics;
// agg written exactly once -> no zero-init of agg needed.
// ---------------------------------------------------------------------------
__global__ __launch_bounds__(256) void gather_kernel(
        const float* __restrict__ x,
        const int2* __restrict__ sorted,
        const int* __restrict__ offsets,
        float* __restrict__ agg, int N) {
    int node = (int)((((size_t)blockIdx.x * blockDim.x) + threadIdx.x) >> 6);
    if (node >= N) return;
    int lane = threadIdx.x & 63;

    int j   = offsets[node];
    int end = offsets[node + 1];
    float2 acc = make_float2(0.f, 0.f);
    for (; j + 1 < end; j += 2) {
        int2 s0 = sorted[j];
        int2 s1 = sorted[j + 1];
        float2 v0 = ((const float2*)(x + (size_t)s0.x * D))[lane];
        float2 v1 = ((const float2*)(x + (size_t)s1.x * D))[lane];
        float w0 = __int_as_float(s0.y);
        float w1 = __int_as_float(s1.y);
        acc.x = fmaf(v0.x, w0, acc.x);  acc.y = fmaf(v0.y, w0, acc.y);
        acc.x = fmaf(v1.x, w1, acc.x);  acc.y = fmaf(v1.y, w1, acc.y);
    }
    if (j < end) {
        int2 s0 = sorted[j];
        float2 v0 = ((const float2*)(x + (size_t)s0.x * D))[lane];
        float w0 = __int_as_float(s0.y);
        acc.x = fmaf(v0.x, w0, acc.x);  acc.y = fmaf(v0.y, w0, acc.y);
    }
    ((float2*)(agg + (size_t)node * D))[lane] = acc;
}

// ---------------------------------------------------------------------------
// out = agg @ W2 + b2 (f32 vector ALU; no fp32 MFMA on CDNA4).
// W2 in LDS; 8 rows per wave; A broadcast via v_readlane (VALU pipe, keeps
// the LDS pipe for the 4 W-reads per k-pair). Lane j owns cols j and j+64.
// ---------------------------------------------------------------------------
#define RPW 8   // rows per wave
__global__ __launch_bounds__(256) void gemm_kernel(
        const float* __restrict__ agg,
        const float* __restrict__ W2,
        const float* __restrict__ b2,
        float* __restrict__ out, int N) {
    __shared__ float Ws[D][D];
    for (int i = threadIdx.x; i < D * D / 4; i += blockDim.x)
        ((float4*)Ws)[i] = ((const float4*)W2)[i];
    __syncthreads();

    int lane = threadIdx.x & 63;
    int wave = threadIdx.x >> 6;
    int wavesPerBlock = blockDim.x >> 6;
    int globalWave = blockIdx.x * wavesPerBlock + wave;
    int totalWaves = gridDim.x * wavesPerBlock;

    float bj0 = b2[lane], bj1 = b2[lane + 64];

    for (int r0 = globalWave * RPW; r0 < N; r0 += totalWaves * RPW) {
        int nr = N - r0;  if (nr > RPW) nr = RPW;
        float2 a2[RPW];
        float acc0[RPW], acc1[RPW];
        #pragma unroll
        for (int i = 0; i < RPW; ++i) {
            a2[i] = (i < nr) ? ((const float2*)(agg + (size_t)(r0 + i) * D))[lane]
                             : make_float2(0.f, 0.f);
            acc0[i] = bj0;  acc1[i] = bj1;
        }
        #pragma unroll 8
        for (int kk = 0; kk < 64; ++kk) {          // covers k = 2kk, 2kk+1
            float w00 = Ws[2 * kk][lane];
            float w01 = Ws[2 * kk][lane + 64];
            float w10 = Ws[2 * kk + 1][lane];
            float w11 = Ws[2 * kk + 1][lane + 64];
            #pragma unroll
            for (int i = 0; i < RPW; ++i) {
                float a0 = __int_as_float(__builtin_amdgcn_readlane(__float_as_int(a2[i].x), kk));
                float a1 = __int_as_float(__builtin_amdgcn_readlane(__float_as_int(a2[i].y), kk));
                acc0[i] = fmaf(a0, w00, acc0[i]);
                acc1[i] = fmaf(a0, w01, acc1[i]);
                acc0[i] = fmaf(a1, w10, acc0[i]);
                acc1[i] = fmaf(a1, w11, acc1[i]);
            }
        }
        #pragma unroll
        for (int i = 0; i < RPW; ++i) {
            if (i < nr) {
                float* o = out + (size_t)(r0 + i) * D;
                o[lane]      = acc0[i];
                o[lane + 64] = acc1[i];
            }
        }
    }
}

extern "C" void kernel_launch(void* const* d_in, const int* in_sizes, int n_in,
                              void* d_out, int out_size, void* d_ws, size_t ws_size,
                              hipStream_t stream) {
    // inputs: 0=x[N,128] f32, 1=edge_index[2,E] int32, 2=edge_weight[E] f32,
    //         3=W1 (dead), 4=b1 (dead), 5=W2[128,128] f32, 6=b2[128] f32
    const float* x  = (const float*)d_in[0];
    const int*   ei = (const int*)d_in[1];
    const float* ew = (const float*)d_in[2];
    const float* W2 = (const float*)d_in[5];
    const float* b2 = (const float*)d_in[6];
    float* out = (float*)d_out;

    int N = in_sizes[0] / D;   // 100000
    int E = in_sizes[2];       // 1600000

    // scratch layout:
    //   d_ws : agg [N*D] f32                         (51.2 MB)
    //   d_out: CSR build area, consumed before GEMM overwrites d_out:
    //     [0, 8E)       int2 sorted[E]      12.8 MB
    //     [8E, ...)     int offsets[N+1], cursor[N], counts[N],
    //                   partials[nP]
    float* agg = (float*)d_ws;
    char* scratch = (char*)d_out;
    int2* sorted  = (int2*)scratch;
    int* offsets  = (int*)(scratch + (size_t)E * 8);
    int* cursor   = offsets + (N + 1);
    int* counts   = cursor + N;
    int* partials = counts + N;

    int nP = (N + SCAN_CHUNK - 1) / SCAN_CHUNK;   // 98 for N=100000

    zero_ints<<<(N + 255) / 256, 256, 0, stream>>>(counts, N);

    hist_kernel<<<(E + 255) / 256, 256, 0, stream>>>(ei, counts, E);

    scan_partials_reduce<<<nP, SCAN_BT, 0, stream>>>(counts, partials, N);
    scan_partials_scan<<<1, 1024, 0, stream>>>(partials, offsets, nP, N);
    scan_final<<<nP, SCAN_BT, 0, stream>>>(counts, partials, offsets, cursor, N);

    bucket_kernel<<<(E + 255) / 256, 256, 0, stream>>>(ei, ew, cursor, sorted, E);

    // one wave per node: N*64 threads
    gather_kernel<<<(N * 64 + 255) / 256, 256, 0, stream>>>(x, sorted, offsets, agg, N);

    gemm_kernel<<<1024, 256, 0, stream>>>(agg, W2, b2, out, N);
}

// Round 4
// 326.803 us; speedup vs baseline: 4.6629x; 1.2593x over previous
//
#include <hip/hip_runtime.h>

#define D 128

typedef __attribute__((ext_vector_type(4))) float f32x4;
typedef __attribute__((ext_vector_type(8))) short bf16x8;

// round-to-nearest-even f32 -> bf16 (manual; inputs are normal floats)
__device__ __forceinline__ unsigned short f2bf(float f) {
    unsigned u = __float_as_uint(f);
    u += 0x7FFFu + ((u >> 16) & 1u);
    return (unsigned short)(u >> 16);
}
__device__ __forceinline__ unsigned pack2(float a, float b) {
    return (unsigned)f2bf(a) | ((unsigned)f2bf(b) << 16);
}

// ---------------------------------------------------------------------------
// x f32 [N*D] -> packed bf16 pairs (low = even element)
// ---------------------------------------------------------------------------
__global__ __launch_bounds__(256) void cvt_x_kernel(
        const float4* __restrict__ x4, uint2* __restrict__ xb, int n4) {
    int i = blockIdx.x * blockDim.x + threadIdx.x;
    int stride = gridDim.x * blockDim.x;
    for (; i < n4; i += stride) {
        float4 v = x4[i];
        xb[i] = make_uint2(pack2(v.x, v.y), pack2(v.z, v.w));
    }
}

__global__ void zero_ints(int* __restrict__ p, int n) {
    int i = blockIdx.x * blockDim.x + threadIdx.x;
    if (i < n) p[i] = 0;
}

__global__ __launch_bounds__(256) void hist_kernel(
        const int* __restrict__ ei, int* __restrict__ counts, int E) {
    int e = blockIdx.x * blockDim.x + threadIdx.x;
    if (e < E) atomicAdd(&counts[ei[E + e]], 1);
}

// ---------------------------------------------------------------------------
// multi-block exclusive scan: counts[n] -> offsets[n+1] (+ cursor copy)
// ---------------------------------------------------------------------------
#define SCAN_BT 256
#define SCAN_IT 4
#define SCAN_CHUNK (SCAN_BT * SCAN_IT)

__global__ __launch_bounds__(SCAN_BT) void scan_partials_reduce(
        const int* __restrict__ counts, int* __restrict__ partials, int n) {
    __shared__ int sh[SCAN_BT];
    int t = threadIdx.x;
    int base = blockIdx.x * SCAN_CHUNK;
    int s = 0;
    #pragma unroll
    for (int j = 0; j < SCAN_IT; ++j) {
        int i = base + t * SCAN_IT + j;
        if (i < n) s += counts[i];
    }
    sh[t] = s;
    __syncthreads();
    for (int off = SCAN_BT / 2; off > 0; off >>= 1) {
        if (t < off) sh[t] += sh[t + off];
        __syncthreads();
    }
    if (t == 0) partials[blockIdx.x] = sh[0];
}

__global__ __launch_bounds__(1024) void scan_partials_scan(
        int* __restrict__ partials, int* __restrict__ offsets, int nP, int n) {
    __shared__ int sh[1024];
    int t = threadIdx.x;
    int v = (t < nP) ? partials[t] : 0;
    sh[t] = v;
    __syncthreads();
    int val = v;
    for (int off = 1; off < 1024; off <<= 1) {
        int other = (t >= off) ? sh[t - off] : 0;
        __syncthreads();
        val += other;
        sh[t] = val;
        __syncthreads();
    }
    if (t < nP) partials[t] = val - v;
    if (t == 1023) offsets[n] = val;
}

__global__ __launch_bounds__(SCAN_BT) void scan_final(
        const int* __restrict__ counts, const int* __restrict__ partials,
        int* __restrict__ offsets, int* __restrict__ cursor, int n) {
    __shared__ int sh[SCAN_BT];
    int t = threadIdx.x;
    int base = blockIdx.x * SCAN_CHUNK;
    int i0 = base + t * SCAN_IT;
    int c[SCAN_IT], pre[SCAN_IT];
    int run = 0;
    #pragma unroll
    for (int j = 0; j < SCAN_IT; ++j) {
        int i = i0 + j;
        c[j] = (i < n) ? counts[i] : 0;
        pre[j] = run;
        run += c[j];
    }
    sh[t] = run;
    __syncthreads();
    int val = run;
    for (int off = 1; off < SCAN_BT; off <<= 1) {
        int other = (t >= off) ? sh[t - off] : 0;
        __syncthreads();
        val += other;
        sh[t] = val;
        __syncthreads();
    }
    int excl = partials[blockIdx.x] + val - run;
    #pragma unroll
    for (int j = 0; j < SCAN_IT; ++j) {
        int i = i0 + j;
        if (i < n) {
            int o = excl + pre[j];
            offsets[i] = o;
            cursor[i]  = o;
        }
    }
}

// ---------------------------------------------------------------------------
// bucket: sorted[pos] = (src << 15) | w15   (4B record; w quantized to 15b)
// ---------------------------------------------------------------------------
__global__ __launch_bounds__(256) void bucket_kernel(
        const int* __restrict__ ei, const float* __restrict__ ew,
        int* __restrict__ cursor, unsigned* __restrict__ sorted, int E) {
    int e = blockIdx.x * blockDim.x + threadIdx.x;
    if (e >= E) return;
    int src = ei[e];
    int dst = ei[E + e];
    float w = ew[e];
    unsigned w15 = (unsigned)__float2int_rn(w * 32768.f);
    if (w15 > 32767u) w15 = 32767u;
    int pos = atomicAdd(&cursor[dst], 1);
    sorted[pos] = ((unsigned)src << 15) | w15;
}

// ---------------------------------------------------------------------------
// gather: one wave per node; lane owns cols 2l,2l+1 (one packed uint).
// reads bf16 x rows (256B coalesced), accumulates f32, writes bf16 agg.
// ---------------------------------------------------------------------------
__global__ __launch_bounds__(256) void gather_kernel(
        const unsigned* __restrict__ xb,      // [N][64] packed bf16x2
        const unsigned* __restrict__ sorted,
        const int* __restrict__ offsets,
        unsigned* __restrict__ aggb, int N) { // [N][64] packed bf16x2
    int node = (int)((((size_t)blockIdx.x * blockDim.x) + threadIdx.x) >> 6);
    if (node >= N) return;
    int lane = threadIdx.x & 63;

    int j   = offsets[node];
    int end = offsets[node + 1];
    float ax = 0.f, ay = 0.f;
    for (; j + 1 < end; j += 2) {
        unsigned p0 = sorted[j];
        unsigned p1 = sorted[j + 1];
        unsigned v0 = xb[(size_t)(p0 >> 15) * 64 + lane];
        unsigned v1 = xb[(size_t)(p1 >> 15) * 64 + lane];
        float w0 = (float)(p0 & 32767u) * (1.f / 32768.f);
        float w1 = (float)(p1 & 32767u) * (1.f / 32768.f);
        ax = fmaf(__uint_as_float(v0 << 16), w0, ax);
        ay = fmaf(__uint_as_float(v0 & 0xFFFF0000u), w0, ay);
        ax = fmaf(__uint_as_float(v1 << 16), w1, ax);
        ay = fmaf(__uint_as_float(v1 & 0xFFFF0000u), w1, ay);
    }
    if (j < end) {
        unsigned p0 = sorted[j];
        unsigned v0 = xb[(size_t)(p0 >> 15) * 64 + lane];
        float w0 = (float)(p0 & 32767u) * (1.f / 32768.f);
        ax = fmaf(__uint_as_float(v0 << 16), w0, ax);
        ay = fmaf(__uint_as_float(v0 & 0xFFFF0000u), w0, ay);
    }
    aggb[(size_t)node * 64 + lane] = pack2(ax, ay);
}

// ---------------------------------------------------------------------------
// out = agg_bf16 @ W2 + b2 via mfma_f32_16x16x32_bf16.
// W2 f32 [k][j] converted+transposed+XOR-swizzled into 32KB LDS per block.
// LDS layout: col-major rows of W2^T: col*256B; 16B chunk c stored at
// chunk (c ^ (col&15))  -> kills the 32-way D=128 column bank conflict.
// Fragments: A[lane&15][(lane>>4)*8+i], B[(lane>>4)*8+i][lane&15],
// C/D: col=lane&15, row=(lane>>4)*4+reg  [m89-verified].
// Wave handles 16 rows x 128 cols; block = 4 waves = 64 rows.
// ---------------------------------------------------------------------------
__global__ __launch_bounds__(256) void gemm_mfma_kernel(
        const unsigned short* __restrict__ aggb,  // [N][128] bf16
        const float* __restrict__ W2,             // [128][128] f32
        const float* __restrict__ b2,
        float* __restrict__ out, int N) {
    __shared__ unsigned short Bl[D * D];   // 32KB
    int t = threadIdx.x;
    #pragma unroll
    for (int q = 0; q < 16; ++q) {
        int idx4 = q * 256 + t;           // float4 index into W2
        float4 v = ((const float4*)W2)[idx4];
        int e = idx4 * 4;
        int k = e >> 7;                    // W2 row (k)
        int j0 = e & 127;                  // W2 col start
        float vv[4] = {v.x, v.y, v.z, v.w};
        #pragma unroll
        for (int m = 0; m < 4; ++m) {
            int col = j0 + m;
            int byte = col * 256 + ((((k >> 3) ^ (col & 15)) << 4) | ((2 * k) & 15));
            *(unsigned short*)((char*)Bl + byte) = f2bf(vv[m]);
        }
    }
    __syncthreads();

    int wave = t >> 6, lane = t & 63;
    int row0 = (blockIdx.x * 4 + wave) * 16;
    if (row0 >= N) return;
    int r = lane & 15, g = lane >> 4;

    const unsigned short* arow = aggb + (size_t)(row0 + r) * D + g * 8;
    bf16x8 afr[4];
    #pragma unroll
    for (int kk = 0; kk < 4; ++kk)
        afr[kk] = *(const bf16x8*)(arow + kk * 32);

    f32x4 acc[8];
    #pragma unroll
    for (int j = 0; j < 8; ++j) acc[j] = (f32x4){0.f, 0.f, 0.f, 0.f};

    #pragma unroll
    for (int j = 0; j < 8; ++j) {
        int col = j * 16 + r;
        const char* cbase = (const char*)Bl + col * 256;
        int cx = col & 15;
        #pragma unroll
        for (int kk = 0; kk < 4; ++kk) {
            bf16x8 b = *(const bf16x8*)(cbase + ((((kk << 2) + g) ^ cx) << 4));
            acc[j] = __builtin_amdgcn_mfma_f32_16x16x32_bf16(afr[kk], b, acc[j], 0, 0, 0);
        }
    }

    #pragma unroll
    for (int j = 0; j < 8; ++j) {
        int col = j * 16 + r;
        float bias = b2[col];
        float* o = out + (size_t)(row0 + g * 4) * D + col;
        o[0]     = acc[j][0] + bias;
        o[D]     = acc[j][1] + bias;
        o[2 * D] = acc[j][2] + bias;
        o[3 * D] = acc[j][3] + bias;
    }
}

extern "C" void kernel_launch(void* const* d_in, const int* in_sizes, int n_in,
                              void* d_out, int out_size, void* d_ws, size_t ws_size,
                              hipStream_t stream) {
    // inputs: 0=x[N,128] f32, 1=edge_index[2,E] int32, 2=edge_weight[E] f32,
    //         3=W1 (dead), 4=b1 (dead), 5=W2[128,128] f32, 6=b2[128] f32
    const float* x  = (const float*)d_in[0];
    const int*   ei = (const int*)d_in[1];
    const float* ew = (const float*)d_in[2];
    const float* W2 = (const float*)d_in[5];
    const float* b2 = (const float*)d_in[6];
    float* out = (float*)d_out;

    int N = in_sizes[0] / D;   // 100000
    int E = in_sizes[2];       // 1600000

    // scratch layout:
    //   d_ws : aggb [N*64] uint (25.6MB) | xb [N*64] uint (25.6MB)  = 51.2MB
    //   d_out (overwritten only by final GEMM):
    //     sorted [E] uint (6.4MB) | offsets[N+1] | cursor[N] | counts[N] | partials
    unsigned* aggb = (unsigned*)d_ws;
    unsigned* xb   = aggb + (size_t)N * 64;
    char* scratch  = (char*)d_out;
    unsigned* sorted = (unsigned*)scratch;
    int* offsets  = (int*)(scratch + (size_t)E * 4);
    int* cursor   = offsets + (N + 1);
    int* counts   = cursor + N;
    int* partials = counts + N;

    int nP = (N + SCAN_CHUNK - 1) / SCAN_CHUNK;

    cvt_x_kernel<<<2048, 256, 0, stream>>>((const float4*)x, (uint2*)xb, N * D / 4);

    zero_ints<<<(N + 255) / 256, 256, 0, stream>>>(counts, N);

    hist_kernel<<<(E + 255) / 256, 256, 0, stream>>>(ei, counts, E);

    scan_partials_reduce<<<nP, SCAN_BT, 0, stream>>>(counts, partials, N);
    scan_partials_scan<<<1, 1024, 0, stream>>>(partials, offsets, nP, N);
    scan_final<<<nP, SCAN_BT, 0, stream>>>(counts, partials, offsets, cursor, N);

    bucket_kernel<<<(E + 255) / 256, 256, 0, stream>>>(ei, ew, cursor, sorted, E);

    gather_kernel<<<(N * 64 + 255) / 256, 256, 0, stream>>>(xb, sorted, offsets, aggb, N);

    gemm_mfma_kernel<<<(N / 16 + 3) / 4, 256, 0, stream>>>(
        (const unsigned short*)aggb, W2, b2, out, N);
}